// Round 6
// baseline (423.212 us; speedup 1.0000x reference)
//
#include <hip/hip_runtime.h>
#include <math.h>

#define D_CHEB 24

typedef __attribute__((ext_vector_type(8))) short bf16x8;
typedef __attribute__((ext_vector_type(4))) short bf16x4;
typedef __attribute__((ext_vector_type(4))) float f32x4;
typedef __attribute__((ext_vector_type(4))) unsigned int u32x4;
typedef __attribute__((ext_vector_type(2))) unsigned int u32x2;

#if __has_builtin(__builtin_amdgcn_mfma_f32_16x16x16bf16_1k)
#define HAVE_MFMA16 1
#else
#define HAVE_MFMA16 0
#endif

struct Cheb {
    float c[D_CHEB + 1];  // c[1..D] pre-halved on host (b' = 0.5 b trick)
    float sm;   // S2 = sm*A + sbd*I
    float sbd;
};

// split 8 f32 (two f32x4) into bf16 hi (RNE) + lo (trunc of residual)
__device__ __forceinline__ void split8(const f32x4 a, const f32x4 b,
                                       bf16x8& hi, bf16x8& lo)
{
    float v[8] = {a[0], a[1], a[2], a[3], b[0], b[1], b[2], b[3]};
    unsigned h16[8], l16[8];
    #pragma unroll
    for (int j = 0; j < 8; ++j) {
        unsigned u = __float_as_uint(v[j]);
        unsigned r = (u + 0x7FFFu + ((u >> 16) & 1u)) >> 16;   // RNE to bf16
        h16[j] = r;
        float res = v[j] - __uint_as_float(r << 16);
        l16[j] = __float_as_uint(res) >> 16;                    // trunc residual
    }
    unsigned hw[4], lw[4];
    #pragma unroll
    for (int q = 0; q < 4; ++q) {
        hw[q] = h16[2 * q] | (h16[2 * q + 1] << 16);
        lw[q] = l16[2 * q] | (l16[2 * q + 1] << 16);
    }
    hi = __builtin_bit_cast(bf16x8, (u32x4){hw[0], hw[1], hw[2], hw[3]});
    lo = __builtin_bit_cast(bf16x8, (u32x4){lw[0], lw[1], lw[2], lw[3]});
}

// ---------------------------------------------------------------------------
// split W (48x96 row-major f32) -> bf16 hi/lo, 5 matrices
// ---------------------------------------------------------------------------
__global__ __launch_bounds__(256) void split_w(
    const float* __restrict__ w0, const float* __restrict__ w1,
    const float* __restrict__ w2, const float* __restrict__ w3,
    const float* __restrict__ w4,
    unsigned short* __restrict__ whi, unsigned short* __restrict__ wlo)
{
    const float* W = (blockIdx.x == 0) ? w0 : (blockIdx.x == 1) ? w1
                   : (blockIdx.x == 2) ? w2 : (blockIdx.x == 3) ? w3 : w4;
    const int base = blockIdx.x * 4608;
    for (int e = threadIdx.x; e < 4608; e += 256) {
        float f = W[e];
        unsigned u = __float_as_uint(f);
        unsigned r = (u + 0x7FFFu + ((u >> 16) & 1u)) >> 16;
        whi[base + e] = (unsigned short)r;
        float res = f - __uint_as_float(r << 16);
        wlo[base + e] = (unsigned short)(__float_as_uint(res) >> 16);
    }
}

// ---------------------------------------------------------------------------
// bimap via split-bf16 MFMA: out = W x W^T. One wave per matrix(-pair).
// ---------------------------------------------------------------------------
#define TLP 104   // T row pitch (f32)
__global__ __launch_bounds__(64, 3) void bimap_kernel(
    const float* __restrict__ x1, const float* __restrict__ x2,
    const unsigned short* __restrict__ whi,
    const unsigned short* __restrict__ wlo,
    float* __restrict__ mats)
{
    __shared__ float Tlds[48 * TLP];
    const int bid = blockIdx.x, l = threadIdx.x;
    const int lc = l & 15, lg = l >> 4;

    const float* x; int wi[2]; size_t oo[2]; int npass;
    if (bid < 4096) {
        int b = bid >> 7, s = (bid >> 6) & 1, m = bid & 63;
        x = (s ? x2 : x1) + (size_t)(b * 64 + m) * 9216;
        wi[0] = s ? 2 : 0;  // wk
        wi[1] = s ? 3 : 1;  // wv
        oo[0] = (size_t)bid; oo[1] = (size_t)(4096 + bid); npass = 2;
    } else {
        int b = bid - 4096;
        x = x2 + (size_t)(b * 64 + 63) * 9216;
        wi[0] = 4; wi[1] = 4;
        oo[0] = (size_t)(8192 + b); oo[1] = oo[0]; npass = 1;
    }

    for (int pass = 0; pass < npass; ++pass) {
        const unsigned short* Wh = whi + wi[pass] * 4608;
        const unsigned short* Wl = wlo + wi[pass] * 4608;

        // ---- phase 1: T(48x96) = W @ x, K=96 ----
        f32x4 C[3][6];
        #pragma unroll
        for (int tr = 0; tr < 3; ++tr)
            #pragma unroll
            for (int tc = 0; tc < 6; ++tc)
                C[tr][tc] = (f32x4){0.f, 0.f, 0.f, 0.f};
        #pragma unroll
        for (int kb = 0; kb < 3; ++kb) {
            bf16x8 ah[3], al[3];
            #pragma unroll
            for (int tr = 0; tr < 3; ++tr) {
                const int off = (16 * tr + lc) * 96 + kb * 32 + lg * 8;
                ah[tr] = *(const bf16x8*)(Wh + off);
                al[tr] = *(const bf16x8*)(Wl + off);
            }
            #pragma unroll
            for (int tc = 0; tc < 6; ++tc) {
                const float* xp = x + (16 * tc + lc) * 96 + kb * 32 + lg * 8;
                bf16x8 bh, bl;
                split8(*(const f32x4*)xp, *(const f32x4*)(xp + 4), bh, bl);
                #pragma unroll
                for (int tr = 0; tr < 3; ++tr) {
                    C[tr][tc] = __builtin_amdgcn_mfma_f32_16x16x32_bf16(ah[tr], bh, C[tr][tc], 0, 0, 0);
                    C[tr][tc] = __builtin_amdgcn_mfma_f32_16x16x32_bf16(ah[tr], bl, C[tr][tc], 0, 0, 0);
                    C[tr][tc] = __builtin_amdgcn_mfma_f32_16x16x32_bf16(al[tr], bh, C[tr][tc], 0, 0, 0);
                }
            }
        }
        #pragma unroll
        for (int tr = 0; tr < 3; ++tr)
            #pragma unroll
            for (int tc = 0; tc < 6; ++tc)
                #pragma unroll
                for (int q = 0; q < 4; ++q)
                    Tlds[(16 * tr + 4 * lg + q) * TLP + 16 * tc + lc] = C[tr][tc][q];

        // ---- phase 2: out(48x48) = T @ W^T, K=96 ----
        f32x4 D[3][3];
        #pragma unroll
        for (int tr = 0; tr < 3; ++tr)
            #pragma unroll
            for (int tc = 0; tc < 3; ++tc)
                D[tr][tc] = (f32x4){0.f, 0.f, 0.f, 0.f};
        #pragma unroll
        for (int kb = 0; kb < 3; ++kb) {
            bf16x8 ah[3], al[3];
            #pragma unroll
            for (int tr = 0; tr < 3; ++tr) {
                const float* tp = &Tlds[(16 * tr + lc) * TLP + kb * 32 + lg * 8];
                split8(*(const f32x4*)tp, *(const f32x4*)(tp + 4), ah[tr], al[tr]);
            }
            #pragma unroll
            for (int tc = 0; tc < 3; ++tc) {
                const int off = (16 * tc + lc) * 96 + kb * 32 + lg * 8;
                bf16x8 bh = *(const bf16x8*)(Wh + off);
                bf16x8 bl = *(const bf16x8*)(Wl + off);
                #pragma unroll
                for (int tr = 0; tr < 3; ++tr) {
                    D[tr][tc] = __builtin_amdgcn_mfma_f32_16x16x32_bf16(ah[tr], bh, D[tr][tc], 0, 0, 0);
                    D[tr][tc] = __builtin_amdgcn_mfma_f32_16x16x32_bf16(ah[tr], bl, D[tr][tc], 0, 0, 0);
                    D[tr][tc] = __builtin_amdgcn_mfma_f32_16x16x32_bf16(al[tr], bh, D[tr][tc], 0, 0, 0);
                }
            }
        }
        float* out = mats + oo[pass] * 2304;
        #pragma unroll
        for (int tr = 0; tr < 3; ++tr)
            #pragma unroll
            for (int tc = 0; tc < 3; ++tc)
                #pragma unroll
                for (int q = 0; q < 4; ++q)
                    out[(16 * tr + 4 * lg + q) * 48 + 16 * tc + lc] = D[tr][tc][q];
    }
}

// ---------------------------------------------------------------------------
// logm: Chebyshev-Clenshaw via split-bf16 MFMA, COLUMN-STRIPED:
// grid (3, nmat); stripe w owns columns [16w,16w+16) of all iterates.
// Column slices evolve independently (b_k[:,S] = ck I[:,S] - b_{k+2}[:,S]
// + S2 @ b_{k+1}[:,S]); S2 lives in registers, so each wave only needs a
// private 16-row Y buffer (4 KB LDS) = high occupancy, no barriers.
// Symmetry: B-frags are row reads of Y-stripe; C tiles written transposed.
// ---------------------------------------------------------------------------
__global__ __launch_bounds__(64, 4) void logm_kernel(float* __restrict__ mats, Cheb co)
{
    __shared__ __align__(16) unsigned short Ybuf[2 * 16 * 64];  // hi @0, lo @+2048B
    char* ldsb = (char*)Ybuf;
    const int l = threadIdx.x;
    const int lc = l & 15, lg = l >> 4;
    const int rloc = lg * 4;
    const int w = blockIdx.x;                 // column stripe 0..2
    float* A = mats + (size_t)blockIdx.y * 2304;

    // ---- A-frags (S2 split, all rows) + seed LDS stripe with split(b'_{D-1})
    bf16x8 Ah[3][2], Al[3][2];
    const float cD = co.c[D_CHEB], cD1 = co.c[D_CHEB - 1];
    #pragma unroll
    for (int tr = 0; tr < 3; ++tr) {
        #pragma unroll
        for (int kb = 0; kb < 2; ++kb) {
            const int row = 16 * tr + lc;
            const int k0 = kb * 32 + lg * 8;
            unsigned shw[4] = {0,0,0,0}, slw[4] = {0,0,0,0};
            unsigned yhw[4] = {0,0,0,0}, ylw[4] = {0,0,0,0};
            if (k0 < 48) {
                const float* ap = A + row * 48 + k0;
                f32x4 a0 = *(const f32x4*)ap;
                f32x4 a1 = *(const f32x4*)(ap + 4);
                float av[8] = {a0[0],a0[1],a0[2],a0[3],a1[0],a1[1],a1[2],a1[3]};
                unsigned sh[8], sl[8], yh[8], yl[8];
                #pragma unroll
                for (int j = 0; j < 8; ++j) {
                    const bool diag = (row == k0 + j);
                    float s = co.sm * av[j] + (diag ? co.sbd : 0.f);
                    float y = cD * s + (diag ? cD1 : 0.f);
                    unsigned us = __float_as_uint(s);
                    sh[j] = us >> 16;
                    sl[j] = __float_as_uint(s - __uint_as_float(us & 0xFFFF0000u)) >> 16;
                    unsigned uy = __float_as_uint(y);
                    yh[j] = uy >> 16;
                    yl[j] = __float_as_uint(y - __uint_as_float(uy & 0xFFFF0000u)) >> 16;
                }
                #pragma unroll
                for (int q = 0; q < 4; ++q) {
                    shw[q] = sh[2*q] | (sh[2*q+1] << 16);
                    slw[q] = sl[2*q] | (sl[2*q+1] << 16);
                    yhw[q] = yh[2*q] | (yh[2*q+1] << 16);
                    ylw[q] = yl[2*q] | (yl[2*q+1] << 16);
                }
            }
            Ah[tr][kb] = __builtin_bit_cast(bf16x8, (u32x4){shw[0],shw[1],shw[2],shw[3]});
            Al[tr][kb] = __builtin_bit_cast(bf16x8, (u32x4){slw[0],slw[1],slw[2],slw[3]});
            if (tr == w) {   // wave-uniform: seed my stripe (local row = lc)
                const int soff = lc * 128 + ((2 * k0) ^ ((lc & 7) << 4));
                *(u32x4*)(ldsb + soff)        = (u32x4){yhw[0],yhw[1],yhw[2],yhw[3]};
                *(u32x4*)(ldsb + 2048 + soff) = (u32x4){ylw[0],ylw[1],ylw[2],ylw[3]};
            }
        }
    }

#if HAVE_MFMA16
    // ---- K=16 tail A-frags: S2[row][32 + 4*lg + j], j=0..3 ----
    bf16x4 Ath[3], Atl[3];
    #pragma unroll
    for (int tr = 0; tr < 3; ++tr) {
        const int row = 16 * tr + lc;
        const int k0 = 32 + 4 * lg;
        f32x4 a = *(const f32x4*)(A + row * 48 + k0);
        unsigned sh[4], sl[4];
        #pragma unroll
        for (int j = 0; j < 4; ++j) {
            const bool diag = (row == k0 + j);
            float s = co.sm * a[j] + (diag ? co.sbd : 0.f);
            unsigned us = __float_as_uint(s);
            sh[j] = us >> 16;
            sl[j] = __float_as_uint(s - __uint_as_float(us & 0xFFFF0000u)) >> 16;
        }
        Ath[tr] = __builtin_bit_cast(bf16x4, (u32x2){sh[0] | (sh[1] << 16), sh[2] | (sh[3] << 16)});
        Atl[tr] = __builtin_bit_cast(bf16x4, (u32x2){sl[0] | (sl[1] << 16), sl[2] | (sl[3] << 16)});
    }
#endif

    // ---- diagonal lane mask (C-layout): dm[q] = (rloc+q == lc) ----
    float dm[4];
    #pragma unroll
    for (int q = 0; q < 4; ++q) dm[q] = (rloc + q == lc) ? 1.f : 0.f;

    // ---- seed C-layout registers (tiles tr=0..2, tc=w) ----
    f32x4 Ya[3], Yb[3];
    #pragma unroll
    for (int t = 0; t < 3; ++t) {
        const int col = 16 * w + lc;
        #pragma unroll
        for (int q = 0; q < 4; ++q) {
            const int row = 16 * t + rloc + q;
            const bool diag = (row == col);
            float a = A[row * 48 + col];
            float s = co.sm * a + (diag ? co.sbd : 0.f);
            Ya[t][q] = cD * s + (diag ? cD1 : 0.f);
            Yb[t][q] = diag ? cD : 0.f;
        }
    }

    // ---- per-lane LDS byte offsets (stripe-local rows = lc) ----
    const int sw = (lc & 7) << 4;
    const int boff0 = lc * 128 + ((16 * lg) ^ sw);        // K 0..31 b128
    const int bofft = lc * 128 + ((64 + 8 * lg) ^ sw);    // K 32..47 b64
    const int boff1 = lc * 128 + ((64 + 16 * lg) ^ sw);   // fallback pad b128
    int woffT[3];
    #pragma unroll
    for (int tr = 0; tr < 3; ++tr)
        woffT[tr] = lc * 128 + ((32 * tr + 8 * lg) ^ sw);

    auto MM = [&](f32x4 (&T)[3]) {
        {   // K chunk 0..31 (16x16x32)
            bf16x8 bh = *(const bf16x8*)(ldsb + boff0);
            bf16x8 bl = *(const bf16x8*)(ldsb + 2048 + boff0);
            #pragma unroll
            for (int tr = 0; tr < 3; ++tr)
                T[tr] = __builtin_amdgcn_mfma_f32_16x16x32_bf16(Ah[tr][0], bh, T[tr], 0, 0, 0);
            #pragma unroll
            for (int tr = 0; tr < 3; ++tr)
                T[tr] = __builtin_amdgcn_mfma_f32_16x16x32_bf16(Ah[tr][0], bl, T[tr], 0, 0, 0);
            #pragma unroll
            for (int tr = 0; tr < 3; ++tr)
                T[tr] = __builtin_amdgcn_mfma_f32_16x16x32_bf16(Al[tr][0], bh, T[tr], 0, 0, 0);
        }
#if HAVE_MFMA16
        {   // K chunk 32..47 (16x16x16 tail)
            bf16x4 bh = *(const bf16x4*)(ldsb + bofft);
            bf16x4 bl = *(const bf16x4*)(ldsb + 2048 + bofft);
            #pragma unroll
            for (int tr = 0; tr < 3; ++tr)
                T[tr] = __builtin_amdgcn_mfma_f32_16x16x16bf16_1k(Ath[tr], bh, T[tr], 0, 0, 0);
            #pragma unroll
            for (int tr = 0; tr < 3; ++tr)
                T[tr] = __builtin_amdgcn_mfma_f32_16x16x16bf16_1k(Ath[tr], bl, T[tr], 0, 0, 0);
            #pragma unroll
            for (int tr = 0; tr < 3; ++tr)
                T[tr] = __builtin_amdgcn_mfma_f32_16x16x16bf16_1k(Atl[tr], bh, T[tr], 0, 0, 0);
        }
#else
        {   // K chunk 32..63 (padded, pad region zero-seeded)
            bf16x8 bh = *(const bf16x8*)(ldsb + boff1);
            bf16x8 bl = *(const bf16x8*)(ldsb + 2048 + boff1);
            #pragma unroll
            for (int tr = 0; tr < 3; ++tr)
                T[tr] = __builtin_amdgcn_mfma_f32_16x16x32_bf16(Ah[tr][1], bh, T[tr], 0, 0, 0);
            #pragma unroll
            for (int tr = 0; tr < 3; ++tr)
                T[tr] = __builtin_amdgcn_mfma_f32_16x16x32_bf16(Ah[tr][1], bl, T[tr], 0, 0, 0);
            #pragma unroll
            for (int tr = 0; tr < 3; ++tr)
                T[tr] = __builtin_amdgcn_mfma_f32_16x16x32_bf16(Al[tr][1], bh, T[tr], 0, 0, 0);
        }
#endif
    };
    // transposed packed write: stored = C^T (valid: all iterates symmetric)
    auto SPLITWT = [&](f32x4 (&T)[3]) {
        #pragma unroll
        for (int t = 0; t < 3; ++t) {
            unsigned u0 = __float_as_uint(T[t][0]);
            unsigned u1 = __float_as_uint(T[t][1]);
            unsigned u2 = __float_as_uint(T[t][2]);
            unsigned u3 = __float_as_uint(T[t][3]);
            unsigned h01 = (u1 & 0xFFFF0000u) | (u0 >> 16);
            unsigned h23 = (u3 & 0xFFFF0000u) | (u2 >> 16);
            float r0 = T[t][0] - __uint_as_float(u0 & 0xFFFF0000u);
            float r1 = T[t][1] - __uint_as_float(u1 & 0xFFFF0000u);
            float r2 = T[t][2] - __uint_as_float(u2 & 0xFFFF0000u);
            float r3 = T[t][3] - __uint_as_float(u3 & 0xFFFF0000u);
            unsigned l01 = (__float_as_uint(r1) & 0xFFFF0000u) | (__float_as_uint(r0) >> 16);
            unsigned l23 = (__float_as_uint(r3) & 0xFFFF0000u) | (__float_as_uint(r2) >> 16);
            const int off = woffT[t];
            *(u32x2*)(ldsb + off)        = (u32x2){h01, h23};
            *(u32x2*)(ldsb + 2048 + off) = (u32x2){l01, l23};
        }
    };
    auto INITK = [&](f32x4 (&T)[3], float ck) {
        #pragma unroll
        for (int t = 0; t < 3; ++t) {
            const float cw = (t == w) ? ck : 0.f;   // wave-uniform select
            #pragma unroll
            for (int q = 0; q < 4; ++q)
                T[t][q] = fmaf(cw, dm[q], -T[t][q]);
        }
    };

    // ---- Clenshaw: b'_k = c'_k I − b'_{k+2} + S2 @ b'_{k+1} ----
    for (int k = D_CHEB - 2; k >= 2; k -= 2) {
        INITK(Yb, co.c[k]);     MM(Yb);  SPLITWT(Yb);
        INITK(Ya, co.c[k - 1]); MM(Ya);  SPLITWT(Ya);
    }
    // ---- final: log = c0 I − 2 b'_2 + S2 @ b'_1  (b'_1 stripe is in LDS) ----
    {
        const float c0w = (w >= 0) ? co.c[0] : 0.f;
        #pragma unroll
        for (int t = 0; t < 3; ++t) {
            const float cw = (t == w) ? c0w : 0.f;
            #pragma unroll
            for (int q = 0; q < 4; ++q)
                Yb[t][q] = fmaf(-2.f, Yb[t][q], cw * dm[q]);
        }
    }
    MM(Yb);
    #pragma unroll
    for (int t = 0; t < 3; ++t)
        #pragma unroll
        for (int q = 0; q < 4; ++q)
            A[(16 * t + rloc + q) * 48 + 16 * w + lc] = Yb[t][q];
}

// ---------------------------------------------------------------------------
// attention, split: energy (4096 waves) -> softmax (32 waves) -> mix (288 blk)
// ---------------------------------------------------------------------------
__global__ __launch_bounds__(64) void energy_kernel(const float* __restrict__ mats,
                                                    float* __restrict__ sc)
{
    const int i = blockIdx.x, b = blockIdx.y, lane = threadIdx.x;
    const float* K = mats + (size_t)(b * 128 + i) * 2304;
    const float* Q = mats + (size_t)(8192 + b) * 2304;
    float p = 0.f;
    #pragma unroll
    for (int j = 0; j < 9; ++j) {
        int f = (lane + 64 * j) * 4;
        float4 kv = *(const float4*)(K + f);
        float4 qv = *(const float4*)(Q + f);
        float dx = kv.x - qv.x, dy = kv.y - qv.y, dz = kv.z - qv.z, dw = kv.w - qv.w;
        p += dx * dx + dy * dy + dz * dz + dw * dw;
    }
    #pragma unroll
    for (int off = 32; off >= 1; off >>= 1) p += __shfl_xor(p, off, 64);
    if (lane == 0)
        sc[b * 128 + i] = 1.f / (1.f + log1pf(fmaxf(p, 0.f)));
}

__global__ __launch_bounds__(64) void softmax_kernel(float* __restrict__ sc)
{
    const int b = blockIdx.x, lane = threadIdx.x;
    float s0 = sc[b * 128 + lane], s1 = sc[b * 128 + 64 + lane];
    float m = fmaxf(s0, s1);
    #pragma unroll
    for (int off = 32; off >= 1; off >>= 1) m = fmaxf(m, __shfl_xor(m, off, 64));
    float e0 = expf(s0 - m), e1 = expf(s1 - m);
    float sum = e0 + e1;
    #pragma unroll
    for (int off = 32; off >= 1; off >>= 1) sum += __shfl_xor(sum, off, 64);
    sc[b * 128 + lane] = e0 / sum;
    sc[b * 128 + 64 + lane] = e1 / sum;
}

__global__ __launch_bounds__(256) void mix_kernel(const float* __restrict__ mats,
                                                  const float* __restrict__ sc,
                                                  float* __restrict__ mixed)
{
    __shared__ float w[128];
    const int b = blockIdx.y, g = blockIdx.x, tid = threadIdx.x;
    if (tid < 128) w[tid] = sc[b * 128 + tid];
    __syncthreads();
    const int e = g * 256 + tid;
    float acc = 0.f;
    for (int i = 0; i < 128; ++i)
        acc += w[i] * mats[(size_t)(4096 + b * 128 + i) * 2304 + e];
    mixed[(size_t)b * 2304 + e] = acc;
}

// ---------------------------------------------------------------------------
// expm via scaling-squaring Taylor (s=2, degree 12). One block per b.
// ---------------------------------------------------------------------------
__global__ __launch_bounds__(256) void expm_kernel(const float* __restrict__ mixed,
                                                   float* __restrict__ out)
{
    __shared__ float Bs[48][49];
    __shared__ float Ra[48][49];
    __shared__ float Rb[48][49];
    const int b = blockIdx.x, tid = threadIdx.x;
    const float* M = mixed + (size_t)b * 2304;
    for (int e = tid; e < 2304; e += 256) {
        int r = e / 48, c = e % 48;
        float v = 0.25f * M[e];
        Bs[r][c] = v;
        Ra[r][c] = ((r == c) ? 1.f : 0.f) + v * (1.f / 12.f);
    }
    __syncthreads();
    const int tr = tid >> 4, tc = tid & 15;
    const int r0 = tr * 3, c0 = tc * 3;
    float* cur = &Ra[0][0];
    float* nxt = &Rb[0][0];
    for (int k = 11; k >= 1; --k) {
        const float invk = 1.f / (float)k;
        float acc[3][3];
        #pragma unroll
        for (int i = 0; i < 3; ++i)
            #pragma unroll
            for (int j = 0; j < 3; ++j) acc[i][j] = 0.f;
        #pragma unroll 4
        for (int kk = 0; kk < 48; ++kk) {
            float a0 = Bs[r0][kk], a1 = Bs[r0 + 1][kk], a2 = Bs[r0 + 2][kk];
            float b0 = cur[kk * 49 + c0], b1 = cur[kk * 49 + c0 + 1], b2 = cur[kk * 49 + c0 + 2];
            acc[0][0] += a0 * b0; acc[0][1] += a0 * b1; acc[0][2] += a0 * b2;
            acc[1][0] += a1 * b0; acc[1][1] += a1 * b1; acc[1][2] += a1 * b2;
            acc[2][0] += a2 * b0; acc[2][1] += a2 * b1; acc[2][2] += a2 * b2;
        }
        #pragma unroll
        for (int i = 0; i < 3; ++i)
            #pragma unroll
            for (int j = 0; j < 3; ++j)
                nxt[(r0 + i) * 49 + (c0 + j)] =
                    ((r0 + i) == (c0 + j) ? 1.f : 0.f) + acc[i][j] * invk;
        __syncthreads();
        float* t = cur; cur = nxt; nxt = t;
    }
    for (int sq = 0; sq < 2; ++sq) {
        float acc[3][3];
        #pragma unroll
        for (int i = 0; i < 3; ++i)
            #pragma unroll
            for (int j = 0; j < 3; ++j) acc[i][j] = 0.f;
        #pragma unroll 4
        for (int kk = 0; kk < 48; ++kk) {
            float a0 = cur[(r0) * 49 + kk], a1 = cur[(r0 + 1) * 49 + kk], a2 = cur[(r0 + 2) * 49 + kk];
            float b0 = cur[kk * 49 + c0], b1 = cur[kk * 49 + c0 + 1], b2 = cur[kk * 49 + c0 + 2];
            acc[0][0] += a0 * b0; acc[0][1] += a0 * b1; acc[0][2] += a0 * b2;
            acc[1][0] += a1 * b0; acc[1][1] += a1 * b1; acc[1][2] += a1 * b2;
            acc[2][0] += a2 * b0; acc[2][1] += a2 * b1; acc[2][2] += a2 * b2;
        }
        __syncthreads();
        #pragma unroll
        for (int i = 0; i < 3; ++i)
            #pragma unroll
            for (int j = 0; j < 3; ++j) nxt[(r0 + i) * 49 + (c0 + j)] = acc[i][j];
        __syncthreads();
        float* t = cur; cur = nxt; nxt = t;
    }
    #pragma unroll
    for (int i = 0; i < 3; ++i)
        #pragma unroll
        for (int j = 0; j < 3; ++j)
            out[(size_t)b * 2304 + (r0 + i) * 48 + (c0 + j)] = cur[(r0 + i) * 49 + (c0 + j)];
}

// ---------------------------------------------------------------------------
extern "C" void kernel_launch(void* const* d_in, const int* in_sizes, int n_in,
                              void* d_out, int out_size, void* d_ws, size_t ws_size,
                              hipStream_t stream)
{
    (void)in_sizes; (void)n_in; (void)out_size; (void)ws_size;
    const float* x1  = (const float*)d_in[0];
    const float* x2  = (const float*)d_in[1];
    const float* wk1 = (const float*)d_in[3];
    const float* wv1 = (const float*)d_in[4];
    const float* wq2 = (const float*)d_in[5];
    const float* wk2 = (const float*)d_in[6];
    const float* wv2 = (const float*)d_in[7];
    float* mats  = (float*)d_ws;                        // [8224][2304]
    float* mixed = mats + (size_t)8224 * 2304;          // [32][2304]
    float* scbuf = mixed + (size_t)32 * 2304;           // [32][128]
    unsigned short* whi = (unsigned short*)(scbuf + 4096);  // [5][4608]
    unsigned short* wlo = whi + 5 * 4608;
    float* out   = (float*)d_out;

    Cheb co;
    {
        const double a = 0.098, bb = 5.5;
        const int N = 256;
        for (int k = 0; k <= D_CHEB; ++k) {
            double sacc = 0.0;
            for (int j = 0; j < N; ++j) {
                double th = M_PI * (j + 0.5) / N;
                double xj = 0.5 * (a + bb) + 0.5 * (bb - a) * cos(th);
                sacc += log(xj) * cos(k * th);
            }
            double ck = 2.0 * sacc / N;
            if (k == 0) ck *= 0.5;
            if (k >= 1) ck *= 0.5;   // fold the final 0.5*S2 into all iterates
            co.c[k] = (float)ck;
        }
        co.sm  = (float)(4.0 / (bb - a));
        co.sbd = (float)((4.0 * 1e-6 - 2.0 * (a + bb)) / (bb - a));
    }

    split_w<<<5, 256, 0, stream>>>(wk1, wv1, wk2, wv2, wq2, whi, wlo);
    bimap_kernel<<<4128, 64, 0, stream>>>(x1, x2, whi, wlo, mats);
    logm_kernel<<<dim3(3, 8224), 64, 0, stream>>>(mats, co);
    energy_kernel<<<dim3(128, 32), 64, 0, stream>>>(mats, scbuf);
    softmax_kernel<<<32, 64, 0, stream>>>(scbuf);
    mix_kernel<<<dim3(9, 32), 256, 0, stream>>>(mats, scbuf, mixed);
    expm_kernel<<<32, 256, 0, stream>>>(mixed, out);
}